// Round 1
// baseline (358.826 us; speedup 1.0000x reference)
//
#include <hip/hip_runtime.h>

#define TOK   65536
#define HID   768
#define NSEQ  128
#define FFD   3072
#define CHUNK 128
#define POOL_THREADS 192   // 192 float4 columns = 768 floats per token row
#define KC 16

__device__ __forceinline__ void add4(float4& a, const float4 b) {
  a.x += b.x; a.y += b.y; a.z += b.z; a.w += b.w;
}

// Segment mean-pool: each block handles 128 consecutive tokens, each thread one
// float4 column. Segment walk is wave-uniform; partial sums (pre-scaled by
// 1/len) flushed with fp32 atomicAdd into pre-zeroed pooled[128][768].
__global__ __launch_bounds__(POOL_THREADS) void pool_kernel(
    const float* __restrict__ x, const int* __restrict__ lens,
    float* __restrict__ pooled) {
  const int t0 = blockIdx.x * CHUNK;
  const int t1 = t0 + CHUNK;
  const int col = threadIdx.x;

  // find segment containing t0 (uniform scalar scan, <=128 iters)
  int seg = 0, cum = 0;
  int L = lens[0];
  while (cum + L <= t0) { cum += L; ++seg; L = lens[seg]; }

  const float4* xv = (const float4*)x + col;
  int t = t0;
  while (t < t1) {
    const int seg_end = cum + L;
    const int run_end = seg_end < t1 ? seg_end : t1;
    const int n = run_end - t;
    const float4* p = xv + (size_t)t * (HID / 4);
    float4 a0 = make_float4(0.f,0.f,0.f,0.f), a1 = a0, a2 = a0, a3 = a0;
    int i = 0;
    for (; i + 4 <= n; i += 4) {
      add4(a0, p[(size_t)(i+0) * (HID/4)]);
      add4(a1, p[(size_t)(i+1) * (HID/4)]);
      add4(a2, p[(size_t)(i+2) * (HID/4)]);
      add4(a3, p[(size_t)(i+3) * (HID/4)]);
    }
    for (; i < n; ++i) add4(a0, p[(size_t)i * (HID/4)]);
    add4(a0, a1); add4(a2, a3); add4(a0, a2);

    const float inv = 1.0f / (float)L;
    float* dst = pooled + (size_t)seg * HID + col * 4;
    atomicAdd(dst + 0, a0.x * inv);
    atomicAdd(dst + 1, a0.y * inv);
    atomicAdd(dst + 2, a0.z * inv);
    atomicAdd(dst + 3, a0.w * inv);

    t = run_end;
    if (run_end == seg_end) {
      cum = seg_end; ++seg;
      if (seg < NSEQ) L = lens[seg];
    }
  }
}

// C[128 x N] += A[128 x Kt] * B[N x Kt]^T over K-chunk [k0, k0+Kchunk).
// Block tile: all 128 rows x 32 cols; thread tile 8s x 2f. C pre-zeroed,
// accumulated with atomicAdd (K split across blockIdx.y).
__global__ __launch_bounds__(256) void gemm_nt(
    const float* __restrict__ A, const float* __restrict__ B,
    float* __restrict__ C, int N, int Kt, int Kchunk) {
  __shared__ float As[KC][132];  // transposed A slice, pad 132 (16B-aligned rows, 2-way max bank alias)
  __shared__ float Bs[KC][34];   // transposed B slice

  const int tid = threadIdx.x;
  const int f0 = blockIdx.x * 32;
  const int k0 = blockIdx.y * Kchunk;
  int kend = k0 + Kchunk; if (kend > Kt) kend = Kt;
  const int fx = (tid & 15) * 2;
  const int sy = (tid >> 4) * 8;

  float acc[8][2];
  #pragma unroll
  for (int i = 0; i < 8; ++i) { acc[i][0] = 0.f; acc[i][1] = 0.f; }

  for (int kc = k0; kc < kend; kc += KC) {
    #pragma unroll
    for (int r = 0; r < 8; ++r) {           // stage A: 128x16, 8/thread, coalesced
      int l = tid + 256 * r;
      int s = l >> 4, kk = l & 15;
      As[kk][s] = A[(size_t)s * Kt + kc + kk];
    }
    #pragma unroll
    for (int r = 0; r < 2; ++r) {           // stage B: 32x16, 2/thread
      int l = tid + 256 * r;
      int f = l >> 4, kk = l & 15;
      Bs[kk][f] = B[(size_t)(f0 + f) * Kt + kc + kk];
    }
    __syncthreads();
    #pragma unroll
    for (int kk = 0; kk < KC; ++kk) {
      const float4 aA = *(const float4*)&As[kk][sy];
      const float4 aB = *(const float4*)&As[kk][sy + 4];
      const float2 bb = *(const float2*)&Bs[kk][fx];
      acc[0][0] += aA.x*bb.x; acc[0][1] += aA.x*bb.y;
      acc[1][0] += aA.y*bb.x; acc[1][1] += aA.y*bb.y;
      acc[2][0] += aA.z*bb.x; acc[2][1] += aA.z*bb.y;
      acc[3][0] += aA.w*bb.x; acc[3][1] += aA.w*bb.y;
      acc[4][0] += aB.x*bb.x; acc[4][1] += aB.x*bb.y;
      acc[5][0] += aB.y*bb.x; acc[5][1] += aB.y*bb.y;
      acc[6][0] += aB.z*bb.x; acc[6][1] += aB.z*bb.y;
      acc[7][0] += aB.w*bb.x; acc[7][1] += aB.w*bb.y;
    }
    __syncthreads();
  }
  #pragma unroll
  for (int i = 0; i < 8; ++i) {
    float* cp = C + (size_t)(sy + i) * N + f0 + fx;
    atomicAdd(cp + 0, acc[i][0]);
    atomicAdd(cp + 1, acc[i][1]);
  }
}

// Row-wise L2 normalize in place: one block per row of out[128][768].
__global__ __launch_bounds__(256) void l2norm_kernel(float* __restrict__ out) {
  const int s = blockIdx.x;
  float* row = out + (size_t)s * HID;
  const int tid = threadIdx.x;
  float v0 = row[tid], v1 = row[tid + 256], v2 = row[tid + 512];
  float ss = v0*v0 + v1*v1 + v2*v2;
  #pragma unroll
  for (int off = 32; off > 0; off >>= 1) ss += __shfl_down(ss, off, 64);
  __shared__ float wsum[4];
  if ((tid & 63) == 0) wsum[tid >> 6] = ss;
  __syncthreads();
  const float tot = wsum[0] + wsum[1] + wsum[2] + wsum[3];
  const float scale = 1.0f / fmaxf(sqrtf(tot), 1e-12f);
  row[tid] = v0 * scale;
  row[tid + 256] = v1 * scale;
  row[tid + 512] = v2 * scale;
}

extern "C" void kernel_launch(void* const* d_in, const int* in_sizes, int n_in,
                              void* d_out, int out_size, void* d_ws, size_t ws_size,
                              hipStream_t stream) {
  const float* x    = (const float*)d_in[0];  // [65536, 768]
  const int*   lens = (const int*)d_in[1];    // [128]
  const float* W1   = (const float*)d_in[2];  // [3072, 768]
  const float* W2   = (const float*)d_in[3];  // [768, 3072]
  float* out = (float*)d_out;                 // [128, 768]

  float* pooled = (float*)d_ws;               // 128*768 fp32
  float* h1     = pooled + NSEQ * HID;        // 128*3072 fp32

  // zero accumulation buffers (ws/out are poisoned 0xAA before each call)
  hipMemsetAsync(d_ws, 0, (size_t)(NSEQ * HID + NSEQ * FFD) * sizeof(float), stream);
  hipMemsetAsync(d_out, 0, (size_t)NSEQ * HID * sizeof(float), stream);

  pool_kernel<<<TOK / CHUNK, POOL_THREADS, 0, stream>>>(x, lens, pooled);
  // gemm1: h1[128,3072] = pooled @ W1^T ; K=768 split 2 ways -> 192 blocks
  gemm_nt<<<dim3(FFD / 32, 2), 256, 0, stream>>>(pooled, W1, h1, FFD, HID, 384);
  // gemm2: out[128,768] = h1 @ W2^T ; K=3072 split 8 ways -> 192 blocks
  gemm_nt<<<dim3(HID / 32, 8), 256, 0, stream>>>(h1, W2, out, HID, FFD, 384);
  l2norm_kernel<<<NSEQ, 256, 0, stream>>>(out);
}

// Round 2
// 355.101 us; speedup vs baseline: 1.0105x; 1.0105x over previous
//
#include <hip/hip_runtime.h>

#define TOK   65536
#define HID   768
#define NSEQ  128
#define FFD   3072
#define CHUNK 64
#define NCHUNK (TOK / CHUNK)   // 1024
#define KS1 5                  // gemm1 k-splits (768 -> 4x160 + 128)
#define KS2 20                 // gemm2 k-splits (3072 -> 19x160 + 32)
#define KCH 160

__device__ __forceinline__ void add4(float4& a, const float4 b) {
  a.x += b.x; a.y += b.y; a.z += b.z; a.w += b.w;
}

// One-block prep: inclusive scan of lens -> incl[128]; per-64-token-chunk
// starting segment id via binary search -> start_seg[1024].
__global__ __launch_bounds__(256) void prep_kernel(
    const int* __restrict__ lens, int* __restrict__ incl,
    int* __restrict__ start_seg) {
  __shared__ int sc[NSEQ];
  const int t = threadIdx.x;
  if (t < NSEQ) sc[t] = lens[t];
  __syncthreads();
  for (int off = 1; off < NSEQ; off <<= 1) {   // Hillis-Steele scan
    int v = 0;
    if (t < NSEQ && t >= off) v = sc[t - off];
    __syncthreads();
    if (t < NSEQ) sc[t] += v;
    __syncthreads();
  }
  if (t < NSEQ) incl[t] = sc[t];
  for (int c = t; c < NCHUNK; c += 256) {
    const int t0 = c * CHUNK;
    int lo = 0, hi = NSEQ - 1;                 // first seg with incl > t0
    while (lo < hi) { int mid = (lo + hi) >> 1; if (sc[mid] <= t0) lo = mid + 1; else hi = mid; }
    start_seg[c] = lo;
  }
}

// Segment mean-pool: block = 64 consecutive tokens, thread = one float4 column.
// Partial sums (pre-scaled 1/len) flushed with fp32 atomicAdd into zeroed pooled.
__global__ __launch_bounds__(192) void pool_kernel(
    const float* __restrict__ x, const int* __restrict__ lens,
    const int* __restrict__ incl, const int* __restrict__ start_seg,
    float* __restrict__ pooled) {
  const int t0 = blockIdx.x * CHUNK;
  const int t1 = t0 + CHUNK;
  const int col = threadIdx.x;

  int seg = start_seg[blockIdx.x];
  int L = lens[seg];
  int cum = incl[seg] - L;

  const float4* xv = (const float4*)x + col;
  int t = t0;
  while (t < t1) {
    const int seg_end = cum + L;
    const int run_end = seg_end < t1 ? seg_end : t1;
    const int n = run_end - t;
    const float4* p = xv + (size_t)t * (HID / 4);
    float4 a0 = make_float4(0.f,0.f,0.f,0.f), a1 = a0, a2 = a0, a3 = a0;
    int i = 0;
    for (; i + 4 <= n; i += 4) {
      add4(a0, p[(size_t)(i+0) * (HID/4)]);
      add4(a1, p[(size_t)(i+1) * (HID/4)]);
      add4(a2, p[(size_t)(i+2) * (HID/4)]);
      add4(a3, p[(size_t)(i+3) * (HID/4)]);
    }
    for (; i < n; ++i) add4(a0, p[(size_t)i * (HID/4)]);
    add4(a0, a1); add4(a2, a3); add4(a0, a2);

    const float inv = 1.0f / (float)L;
    float* dst = pooled + (size_t)seg * HID + col * 4;
    atomicAdd(dst + 0, a0.x * inv);
    atomicAdd(dst + 1, a0.y * inv);
    atomicAdd(dst + 2, a0.z * inv);
    atomicAdd(dst + 3, a0.w * inv);

    t = run_end;
    if (run_end == seg_end) {
      cum = seg_end; ++seg;
      if (seg < NSEQ) L = lens[seg];
    }
  }
}

// Cp[ky][128 x N] = A[128 x Kt] * B[N x Kt]^T over k-range of this ksplit.
// A may itself be a sum of `nsum` partial slabs spaced `pstride` elements.
// Block tile 128s x 64f, thread tile 8s x 4f. No atomics: each block owns its
// full partial slab region.
__global__ __launch_bounds__(256) void gemm_nt(
    const float* __restrict__ A, const float* __restrict__ B,
    float* __restrict__ Cp, int N, int Kt, int nsum, int pstride) {
  __shared__ float As[16][132];  // [k][s], pad->2-way max bank alias (free)
  __shared__ float Bs[16][68];   // [k][f]

  const int tid = threadIdx.x;
  const int f0 = blockIdx.x * 64;
  const int k0 = blockIdx.y * KCH;
  const int kend = (k0 + KCH) < Kt ? (k0 + KCH) : Kt;
  float* C = Cp + (size_t)blockIdx.y * NSEQ * N;
  const int fx = (tid & 15) * 4;
  const int sy = (tid >> 4) * 8;

  float acc[8][4];
  #pragma unroll
  for (int i = 0; i < 8; ++i)
    #pragma unroll
    for (int j = 0; j < 4; ++j) acc[i][j] = 0.f;

  for (int kc = k0; kc < kend; kc += 16) {
    #pragma unroll
    for (int r = 0; r < 2; ++r) {          // stage A: 128x16 as float4 of k
      const int l = tid + 256 * r;
      const int s = l >> 2, k4 = (l & 3) * 4;
      const float* ap = A + (size_t)s * Kt + kc + k4;
      float4 v = *(const float4*)ap;
      for (int p = 1; p < nsum; ++p) {     // fold gemm1 partials during staging
        const float4 w = *(const float4*)(ap + (size_t)p * pstride);
        add4(v, w);
      }
      As[k4 + 0][s] = v.x; As[k4 + 1][s] = v.y;
      As[k4 + 2][s] = v.z; As[k4 + 3][s] = v.w;
    }
    {                                      // stage B: 64x16 as float4 of k
      const int f = tid >> 2, k4 = (tid & 3) * 4;
      const float4 v = *(const float4*)(B + (size_t)(f0 + f) * Kt + kc + k4);
      Bs[k4 + 0][f] = v.x; Bs[k4 + 1][f] = v.y;
      Bs[k4 + 2][f] = v.z; Bs[k4 + 3][f] = v.w;
    }
    __syncthreads();
    #pragma unroll
    for (int kk = 0; kk < 16; ++kk) {
      const float4 aA = *(const float4*)&As[kk][sy];
      const float4 aB = *(const float4*)&As[kk][sy + 4];
      const float4 bb = *(const float4*)&Bs[kk][fx];
      acc[0][0] += aA.x*bb.x; acc[0][1] += aA.x*bb.y; acc[0][2] += aA.x*bb.z; acc[0][3] += aA.x*bb.w;
      acc[1][0] += aA.y*bb.x; acc[1][1] += aA.y*bb.y; acc[1][2] += aA.y*bb.z; acc[1][3] += aA.y*bb.w;
      acc[2][0] += aA.z*bb.x; acc[2][1] += aA.z*bb.y; acc[2][2] += aA.z*bb.z; acc[2][3] += aA.z*bb.w;
      acc[3][0] += aA.w*bb.x; acc[3][1] += aA.w*bb.y; acc[3][2] += aA.w*bb.z; acc[3][3] += aA.w*bb.w;
      acc[4][0] += aB.x*bb.x; acc[4][1] += aB.x*bb.y; acc[4][2] += aB.x*bb.z; acc[4][3] += aB.x*bb.w;
      acc[5][0] += aB.y*bb.x; acc[5][1] += aB.y*bb.y; acc[5][2] += aB.y*bb.z; acc[5][3] += aB.y*bb.w;
      acc[6][0] += aB.z*bb.x; acc[6][1] += aB.z*bb.y; acc[6][2] += aB.z*bb.z; acc[6][3] += aB.z*bb.w;
      acc[7][0] += aB.w*bb.x; acc[7][1] += aB.w*bb.y; acc[7][2] += aB.w*bb.z; acc[7][3] += aB.w*bb.w;
    }
    __syncthreads();
  }
  #pragma unroll
  for (int i = 0; i < 8; ++i) {
    float4 o = make_float4(acc[i][0], acc[i][1], acc[i][2], acc[i][3]);
    *(float4*)(C + (size_t)(sy + i) * N + f0 + fx) = o;
  }
}

// Sum the KS2 gemm2 partials, L2-normalize each row, write d_out.
__global__ __launch_bounds__(256) void norm_kernel(
    const float* __restrict__ outp, float* __restrict__ out) {
  const int s = blockIdx.x;
  const int tid = threadIdx.x;
  float v[3];
  #pragma unroll
  for (int j = 0; j < 3; ++j) {
    const int c = tid + 256 * j;
    float a = 0.f;
    for (int p = 0; p < KS2; ++p)
      a += outp[((size_t)p * NSEQ + s) * HID + c];
    v[j] = a;
  }
  float ss = v[0]*v[0] + v[1]*v[1] + v[2]*v[2];
  #pragma unroll
  for (int off = 32; off > 0; off >>= 1) ss += __shfl_down(ss, off, 64);
  __shared__ float wsum[4];
  if ((tid & 63) == 0) wsum[tid >> 6] = ss;
  __syncthreads();
  const float tot = wsum[0] + wsum[1] + wsum[2] + wsum[3];
  const float scale = 1.0f / fmaxf(sqrtf(tot), 1e-12f);
  #pragma unroll
  for (int j = 0; j < 3; ++j) out[(size_t)s * HID + tid + 256 * j] = v[j] * scale;
}

extern "C" void kernel_launch(void* const* d_in, const int* in_sizes, int n_in,
                              void* d_out, int out_size, void* d_ws, size_t ws_size,
                              hipStream_t stream) {
  const float* x    = (const float*)d_in[0];  // [65536, 768]
  const int*   lens = (const int*)d_in[1];    // [128]
  const float* W1   = (const float*)d_in[2];  // [3072, 768]
  const float* W2   = (const float*)d_in[3];  // [768, 3072]
  float* out = (float*)d_out;                 // [128, 768]

  float* pooled = (float*)d_ws;                                  // 128*768
  float* h1p    = pooled + NSEQ * HID;                           // KS1*128*3072
  float* outp   = h1p + (size_t)KS1 * NSEQ * FFD;                // KS2*128*768
  int*   incl   = (int*)(outp + (size_t)KS2 * NSEQ * HID);       // 128
  int*   start_seg = incl + NSEQ;                                // 1024

  // only pooled needs zeroing (atomic accumulation target)
  hipMemsetAsync(pooled, 0, (size_t)NSEQ * HID * sizeof(float), stream);

  prep_kernel<<<1, 256, 0, stream>>>(lens, incl, start_seg);
  pool_kernel<<<NCHUNK, 192, 0, stream>>>(x, lens, incl, start_seg, pooled);
  // gemm1: h1p[5][128,3072] partials of pooled @ W1^T
  gemm_nt<<<dim3(FFD / 64, KS1), 256, 0, stream>>>(pooled, W1, h1p, FFD, HID, 1, 0);
  // gemm2: outp[20][128,768] partials of (sum h1p) @ W2^T
  gemm_nt<<<dim3(HID / 64, KS2), 256, 0, stream>>>(h1p, W2, outp, HID, FFD, KS1, NSEQ * FFD);
  norm_kernel<<<NSEQ, 256, 0, stream>>>(outp, out);
}